// Round 1
// baseline (718.363 us; speedup 1.0000x reference)
//
#include <hip/hip_runtime.h>
#include <math.h>
#include <float.h>

#define N_NODES 50000
#define N_EDGES 800000
#define D_INP   96
#define D_HID   128
#define N_B     512

// ---------------------------------------------------------------------------
// Weight transposes: Wt_in[k][d] = W_in[d][k]  (96x128)
//                    Wt_g[k][g]  = k<256 ? W_ih[g][k] : W_hh[g][k-256]  (384x512)
__global__ void k_transpose(const float* __restrict__ W_in,
                            const float* __restrict__ W_ih,
                            const float* __restrict__ W_hh,
                            float* __restrict__ Wt_in,
                            float* __restrict__ Wt_g) {
    int idx = blockIdx.x * 256 + threadIdx.x;
    if (idx < D_INP * D_HID) {
        int k = idx / D_HID, d = idx % D_HID;
        Wt_in[idx] = W_in[d * D_INP + k];
    }
    if (idx < 384 * 512) {
        int k = idx / 512, g = idx % 512;
        Wt_g[idx] = (k < 256) ? W_ih[g * 256 + k] : W_hh[g * 128 + (k - 256)];
    }
}

// ---------------------------------------------------------------------------
// CSR build: count in-degree at dst
__global__ void k_count(const int* __restrict__ dst, int* __restrict__ cnt) {
    int e = blockIdx.x * 256 + threadIdx.x;
    if (e < N_EDGES) atomicAdd(&cnt[dst[e]], 1);
}

// Single-block exclusive scan over cnt -> row_ptr; deg_f = max(cnt,1)
__global__ void k_scan(const int* __restrict__ cnt, int* __restrict__ row_ptr,
                       float* __restrict__ deg_f) {
    __shared__ int sm[1024];
    int t = threadIdx.x;
    const int CH = 49;                       // 1024*49 = 50176 >= 50000
    int lo = t * CH, hi = min(lo + CH, N_NODES);
    int s = 0;
    for (int i = lo; i < hi; i++) s += cnt[i];
    sm[t] = s;
    __syncthreads();
    for (int off = 1; off < 1024; off <<= 1) {
        int v = (t >= off) ? sm[t - off] : 0;
        __syncthreads();
        sm[t] += v;
        __syncthreads();
    }
    int run = sm[t] - s;                     // exclusive prefix of this chunk
    for (int i = lo; i < hi; i++) {
        row_ptr[i] = run;
        int c = cnt[i];
        deg_f[i] = (float)max(c, 1);
        run += c;
    }
    if (t == 1023) row_ptr[N_NODES] = sm[1023];
}

// Scatter edge src ids into dst-sorted order
__global__ void k_scatter(const int* __restrict__ src, const int* __restrict__ dst,
                          const int* __restrict__ row_ptr, int* __restrict__ cnt,
                          int* __restrict__ esrc) {
    int e = blockIdx.x * 256 + threadIdx.x;
    if (e < N_EDGES) {
        int d = dst[e];
        int p = row_ptr[d] + atomicAdd(&cnt[d], 1);
        esrc[p] = src[e];
    }
}

// seg_ptr for sorted batch: seg_ptr[b] = first node of graph b; seg_ptr[B]=N
__global__ void k_segptr(const int* __restrict__ batch, int* __restrict__ seg_ptr) {
    int n = blockIdx.x * 256 + threadIdx.x;
    if (n >= N_NODES) return;
    int bc = batch[n];
    int bp = (n == 0) ? -1 : batch[n - 1];
    for (int b = bp + 1; b <= bc; b++) seg_ptr[b] = n;
    if (n == N_NODES - 1)
        for (int b = bc + 1; b <= N_B; b++) seg_ptr[b] = N_NODES;
}

// ---------------------------------------------------------------------------
// Input layer: h = relu(x @ W_in^T + b_in).  Tile 64 nodes x 64 feats,
// thread micro-tile 4x4, K=96 fully staged in LDS.
__global__ __launch_bounds__(256) void k_ingemm(const float* __restrict__ x,
                                                const float* __restrict__ Wt_in,
                                                const float* __restrict__ b_in,
                                                float* __restrict__ h) {
    __shared__ __align__(16) float xs[64 * 96];   // 24 KB
    __shared__ __align__(16) float ws[96 * 64];   // 24 KB
    int n0 = blockIdx.x * 64;
    int d0 = blockIdx.y * 64;
    int tid = threadIdx.x;
    for (int j = tid; j < 64 * 96 / 4; j += 256) {
        int node = n0 + (j * 4) / 96;
        float4 v = make_float4(0.f, 0.f, 0.f, 0.f);
        if (node < N_NODES) v = *(const float4*)&x[n0 * 96 + j * 4];
        *(float4*)&xs[j * 4] = v;
    }
    for (int j = tid; j < 96 * 64 / 4; j += 256) {
        int k = (j * 4) / 64, dd = (j * 4) % 64;
        *(float4*)&ws[j * 4] = *(const float4*)&Wt_in[k * D_HID + d0 + dd];
    }
    __syncthreads();
    int tn = tid / 16;       // node sub-tile (4 nodes)
    int td = tid % 16;       // feat sub-tile (4 feats)
    float acc[4][4] = {};
    for (int k0 = 0; k0 < 96; k0 += 4) {
        float4 w0 = *(float4*)&ws[(k0 + 0) * 64 + td * 4];
        float4 w1 = *(float4*)&ws[(k0 + 1) * 64 + td * 4];
        float4 w2 = *(float4*)&ws[(k0 + 2) * 64 + td * 4];
        float4 w3 = *(float4*)&ws[(k0 + 3) * 64 + td * 4];
#pragma unroll
        for (int j = 0; j < 4; j++) {
            float4 xv = *(float4*)&xs[(tn * 4 + j) * 96 + k0];
            acc[j][0] += xv.x * w0.x + xv.y * w1.x + xv.z * w2.x + xv.w * w3.x;
            acc[j][1] += xv.x * w0.y + xv.y * w1.y + xv.z * w2.y + xv.w * w3.y;
            acc[j][2] += xv.x * w0.z + xv.y * w1.z + xv.z * w2.z + xv.w * w3.z;
            acc[j][3] += xv.x * w0.w + xv.y * w1.w + xv.z * w2.w + xv.w * w3.w;
        }
    }
    float4 bb = *(const float4*)&b_in[d0 + td * 4];
#pragma unroll
    for (int j = 0; j < 4; j++) {
        int node = n0 + tn * 4 + j;
        if (node < N_NODES) {
            float4 o;
            o.x = fmaxf(acc[j][0] + bb.x, 0.f);
            o.y = fmaxf(acc[j][1] + bb.y, 0.f);
            o.z = fmaxf(acc[j][2] + bb.z, 0.f);
            o.w = fmaxf(acc[j][3] + bb.w, 0.f);
            *(float4*)&h[node * D_HID + d0 + td * 4] = o;
        }
    }
}

// ---------------------------------------------------------------------------
// One MPNN step: h_out = (h_in + segmean(h_in[src] at dst)) * 0.5
// 32-lane group per node, float4 per lane (contiguous 512B per gather).
__global__ __launch_bounds__(256) void k_mpnn(const float* __restrict__ hin,
                                              float* __restrict__ hout,
                                              const int* __restrict__ row_ptr,
                                              const int* __restrict__ esrc,
                                              const float* __restrict__ deg_f) {
    int g = threadIdx.x >> 5;
    int l = threadIdx.x & 31;
    int n = blockIdx.x * 8 + g;
    if (n >= N_NODES) return;
    int s0 = row_ptr[n], s1 = row_ptr[n + 1];
    float4 acc = make_float4(0.f, 0.f, 0.f, 0.f);
    for (int i = s0; i < s1; i++) {
        int s = esrc[i];
        float4 v = *(const float4*)&hin[s * D_HID + l * 4];
        acc.x += v.x; acc.y += v.y; acc.z += v.z; acc.w += v.w;
    }
    float invd = 1.0f / deg_f[n];
    float4 hv = *(const float4*)&hin[n * D_HID + l * 4];
    float4 o;
    o.x = (hv.x + acc.x * invd) * 0.5f;
    o.y = (hv.y + acc.y * invd) * 0.5f;
    o.z = (hv.z + acc.z * invd) * 0.5f;
    o.w = (hv.w + acc.w * invd) * 0.5f;
    *(float4*)&hout[n * D_HID + l * 4] = o;
}

// ---------------------------------------------------------------------------
// gates = [q_star | hh] @ Wt_g + (b_ih + b_hh).  Tile: 4 b-rows x 256 gates,
// thread computes 4x2, K=384 (A-tile in LDS, W streamed coalesced).
__global__ __launch_bounds__(128) void k_gates(const float* __restrict__ qstar,
                                               const float* __restrict__ hh,
                                               const float* __restrict__ Wt_g,
                                               const float* __restrict__ b_ih,
                                               const float* __restrict__ b_hh,
                                               float* __restrict__ gates) {
    __shared__ __align__(16) float als[4 * 384];
    int b0 = blockIdx.x * 4;
    int g0 = blockIdx.y * 256;
    int tid = threadIdx.x;
    for (int i = tid; i < 4 * 384; i += 128) {
        int bb = i / 384, k = i % 384;
        als[i] = (k < 256) ? qstar[(b0 + bb) * 256 + k]
                           : hh[(b0 + bb) * 128 + (k - 256)];
    }
    __syncthreads();
    int g = g0 + tid * 2;
    float2 acc0 = {0.f, 0.f}, acc1 = {0.f, 0.f}, acc2 = {0.f, 0.f}, acc3 = {0.f, 0.f};
    for (int k0 = 0; k0 < 384; k0 += 4) {
        float4 a0 = *(float4*)&als[0 * 384 + k0];
        float4 a1 = *(float4*)&als[1 * 384 + k0];
        float4 a2 = *(float4*)&als[2 * 384 + k0];
        float4 a3 = *(float4*)&als[3 * 384 + k0];
        float2 w;
        w = *(const float2*)&Wt_g[(k0 + 0) * 512 + g];
        acc0.x += a0.x * w.x; acc0.y += a0.x * w.y;
        acc1.x += a1.x * w.x; acc1.y += a1.x * w.y;
        acc2.x += a2.x * w.x; acc2.y += a2.x * w.y;
        acc3.x += a3.x * w.x; acc3.y += a3.x * w.y;
        w = *(const float2*)&Wt_g[(k0 + 1) * 512 + g];
        acc0.x += a0.y * w.x; acc0.y += a0.y * w.y;
        acc1.x += a1.y * w.x; acc1.y += a1.y * w.y;
        acc2.x += a2.y * w.x; acc2.y += a2.y * w.y;
        acc3.x += a3.y * w.x; acc3.y += a3.y * w.y;
        w = *(const float2*)&Wt_g[(k0 + 2) * 512 + g];
        acc0.x += a0.z * w.x; acc0.y += a0.z * w.y;
        acc1.x += a1.z * w.x; acc1.y += a1.z * w.y;
        acc2.x += a2.z * w.x; acc2.y += a2.z * w.y;
        acc3.x += a3.z * w.x; acc3.y += a3.z * w.y;
        w = *(const float2*)&Wt_g[(k0 + 3) * 512 + g];
        acc0.x += a0.w * w.x; acc0.y += a0.w * w.y;
        acc1.x += a1.w * w.x; acc1.y += a1.w * w.y;
        acc2.x += a2.w * w.x; acc2.y += a2.w * w.y;
        acc3.x += a3.w * w.x; acc3.y += a3.w * w.y;
    }
    float bias0 = b_ih[g] + b_hh[g];
    float bias1 = b_ih[g + 1] + b_hh[g + 1];
    float2 o;
    o.x = acc0.x + bias0; o.y = acc0.y + bias1;
    *(float2*)&gates[(b0 + 0) * 512 + g] = o;
    o.x = acc1.x + bias0; o.y = acc1.y + bias1;
    *(float2*)&gates[(b0 + 1) * 512 + g] = o;
    o.x = acc2.x + bias0; o.y = acc2.y + bias1;
    *(float2*)&gates[(b0 + 2) * 512 + g] = o;
    o.x = acc3.x + bias0; o.y = acc3.y + bias1;
    *(float2*)&gates[(b0 + 3) * 512 + g] = o;
}

__device__ __forceinline__ float sigmoidf_(float v) { return 1.0f / (1.0f + expf(-v)); }

// LSTM elementwise; writes hh, cc and q into q_star[:, :128]
__global__ void k_lstm(const float* __restrict__ gates, float* __restrict__ hh,
                       float* __restrict__ cc, float* __restrict__ qstar) {
    int idx = blockIdx.x * 256 + threadIdx.x;   // < B*D = 65536
    int b = idx >> 7, dd = idx & 127;
    const float* gr = &gates[b * 512];
    float ig = gr[dd], fg = gr[128 + dd], gg = gr[256 + dd], og = gr[384 + dd];
    float c = sigmoidf_(fg) * cc[idx] + sigmoidf_(ig) * tanhf(gg);
    cc[idx] = c;
    float hv = sigmoidf_(og) * tanhf(c);
    hh[idx] = hv;
    qstar[b * 256 + dd] = hv;
}

// Segment attention: e = h.q[batch], softmax per graph, r = sum a*h.
// One block per graph (batch is sorted -> contiguous node range).
__global__ __launch_bounds__(128) void k_attn(const float* __restrict__ h,
                                              const float* __restrict__ hh,
                                              const int* __restrict__ seg_ptr,
                                              float* __restrict__ e_buf,
                                              float* __restrict__ qstar) {
    int b = blockIdx.x;
    int g = threadIdx.x >> 5, l = threadIdx.x & 31;
    int s0 = seg_ptr[b], s1 = seg_ptr[b + 1];
    float4 q = *(const float4*)&hh[b * 128 + l * 4];
    float lmax = -INFINITY;
    for (int n = s0 + g; n < s1; n += 4) {
        float4 hv = *(const float4*)&h[n * 128 + l * 4];
        float d = hv.x * q.x + hv.y * q.y + hv.z * q.z + hv.w * q.w;
        for (int m = 16; m >= 1; m >>= 1) d += __shfl_xor(d, m, 64);
        if (l == 0) e_buf[n] = d;
        lmax = fmaxf(lmax, d);
    }
    __shared__ float smax[4];
    __shared__ float ssum[4];
    __shared__ __align__(16) float sr[4][128];
    if (l == 0) smax[g] = lmax;
    __syncthreads();
    float M = fmaxf(fmaxf(smax[0], smax[1]), fmaxf(smax[2], smax[3]));
    float4 racc = make_float4(0.f, 0.f, 0.f, 0.f);
    float asum = 0.f;
    for (int n = s0 + g; n < s1; n += 4) {
        float a = expf(e_buf[n] - M);
        asum += a;
        float4 hv = *(const float4*)&h[n * 128 + l * 4];
        racc.x += a * hv.x; racc.y += a * hv.y;
        racc.z += a * hv.z; racc.w += a * hv.w;
    }
    if (l == 0) ssum[g] = asum;
    *(float4*)&sr[g][l * 4] = racc;
    __syncthreads();
    if (g == 0) {
        float4 r0 = *(float4*)&sr[0][l * 4];
        float4 r1 = *(float4*)&sr[1][l * 4];
        float4 r2 = *(float4*)&sr[2][l * 4];
        float4 r3 = *(float4*)&sr[3][l * 4];
        float inv = 1.0f / (ssum[0] + ssum[1] + ssum[2] + ssum[3] + 1e-16f);
        float4 o;
        o.x = (r0.x + r1.x + r2.x + r3.x) * inv;
        o.y = (r0.y + r1.y + r2.y + r3.y) * inv;
        o.z = (r0.z + r1.z + r2.z + r3.z) * inv;
        o.w = (r0.w + r1.w + r2.w + r3.w) * inv;
        *(float4*)&qstar[b * 256 + 128 + l * 4] = o;
    }
}

// out[b] = q_star[b] . W_pred + b_pred  (one wave per b)
__global__ void k_pred(const float* __restrict__ qstar, const float* __restrict__ W_pred,
                       const float* __restrict__ b_pred, float* __restrict__ out) {
    int w = (blockIdx.x * 256 + threadIdx.x) >> 6;
    int l = threadIdx.x & 63;
    if (w >= N_B) return;
    float4 qv = *(const float4*)&qstar[w * 256 + l * 4];
    float4 wv = *(const float4*)&W_pred[l * 4];
    float d = qv.x * wv.x + qv.y * wv.y + qv.z * wv.z + qv.w * wv.w;
    for (int m = 32; m >= 1; m >>= 1) d += __shfl_xor(d, m, 64);
    if (l == 0) out[w] = d + b_pred[0];
}

// ---------------------------------------------------------------------------
extern "C" void kernel_launch(void* const* d_in, const int* in_sizes, int n_in,
                              void* d_out, int out_size, void* d_ws, size_t ws_size,
                              hipStream_t stream) {
    const float* x      = (const float*)d_in[0];
    const int*   edge   = (const int*)d_in[1];
    const int*   batch  = (const int*)d_in[2];
    const float* W_in   = (const float*)d_in[3];
    const float* b_in   = (const float*)d_in[4];
    const float* W_ih   = (const float*)d_in[5];
    const float* W_hh   = (const float*)d_in[6];
    const float* b_ih   = (const float*)d_in[7];
    const float* b_hh   = (const float*)d_in[8];
    const float* W_pred = (const float*)d_in[9];
    const float* b_pred = (const float*)d_in[10];
    float* out = (float*)d_out;

    const int* src = edge;              // edge_index[0]
    const int* dst = edge + N_EDGES;    // edge_index[1]

    // workspace layout (floats first, 16B-aligned throughout)
    float* f = (float*)d_ws;
    float* h0    = f;                     f += (size_t)N_NODES * D_HID;   // 6.4M
    float* h1    = f;                     f += (size_t)N_NODES * D_HID;   // 6.4M
    float* deg_f = f;                     f += N_NODES;
    float* e_buf = f;                     f += N_NODES + 12;              // keep 16B align
    float* qstar = f;                     f += (size_t)N_B * 256;
    float* hh    = f;                     f += (size_t)N_B * 128;
    float* cc    = f;                     f += (size_t)N_B * 128;
    float* gates = f;                     f += (size_t)N_B * 512;
    float* Wt_in = f;                     f += D_INP * D_HID;
    float* Wt_g  = f;                     f += 384 * 512;
    int* ip = (int*)f;
    int* row_ptr = ip;                    ip += N_NODES + 1;
    int* cnt     = ip;                    ip += N_NODES;
    int* esrc    = ip;                    ip += N_EDGES;
    int* seg_ptr = ip;                    ip += N_B + 1;

    // ---- CSR build + seg_ptr + weight transposes
    hipMemsetAsync(cnt, 0, N_NODES * sizeof(int), stream);
    k_transpose<<<768, 256, 0, stream>>>(W_in, W_ih, W_hh, Wt_in, Wt_g);
    k_count<<<(N_EDGES + 255) / 256, 256, 0, stream>>>(dst, cnt);
    k_scan<<<1, 1024, 0, stream>>>(cnt, row_ptr, deg_f);
    hipMemsetAsync(cnt, 0, N_NODES * sizeof(int), stream);
    k_scatter<<<(N_EDGES + 255) / 256, 256, 0, stream>>>(src, dst, row_ptr, cnt, esrc);
    k_segptr<<<(N_NODES + 255) / 256, 256, 0, stream>>>(batch, seg_ptr);

    // ---- input layer
    k_ingemm<<<dim3((N_NODES + 63) / 64, 2), 256, 0, stream>>>(x, Wt_in, b_in, h0);

    // ---- 4 MPNN steps (ping-pong, ends in h0)
    k_mpnn<<<(N_NODES + 7) / 8, 256, 0, stream>>>(h0, h1, row_ptr, esrc, deg_f);
    k_mpnn<<<(N_NODES + 7) / 8, 256, 0, stream>>>(h1, h0, row_ptr, esrc, deg_f);
    k_mpnn<<<(N_NODES + 7) / 8, 256, 0, stream>>>(h0, h1, row_ptr, esrc, deg_f);
    k_mpnn<<<(N_NODES + 7) / 8, 256, 0, stream>>>(h1, h0, row_ptr, esrc, deg_f);

    // ---- Set2Set (q_star, hh, cc are contiguous -> one memset)
    hipMemsetAsync(qstar, 0, (size_t)(N_B * 256 + N_B * 128 + N_B * 128) * sizeof(float), stream);
    for (int step = 0; step < 3; step++) {
        k_gates<<<dim3(N_B / 4, 2), 128, 0, stream>>>(qstar, hh, Wt_g, b_ih, b_hh, gates);
        k_lstm<<<(N_B * 128) / 256, 256, 0, stream>>>(gates, hh, cc, qstar);
        k_attn<<<N_B, 128, 0, stream>>>(h0, hh, seg_ptr, e_buf, qstar);
    }

    // ---- prediction head
    k_pred<<<(N_B * 64) / 256, 256, 0, stream>>>(qstar, W_pred, b_pred, out);
}

// Round 2
// 623.017 us; speedup vs baseline: 1.1530x; 1.1530x over previous
//
#include <hip/hip_runtime.h>
#include <math.h>
#include <float.h>

#define N_NODES 50000
#define N_EDGES 800000
#define D_INP   96
#define D_HID   128
#define N_B     512
#define SCAN_NB 98   // ceil(50000/512)

// ---------------------------------------------------------------------------
// Weight transposes: Wt_in[k][d] = W_in[d][k]  (96x128)
//                    Wt_g[k][g]  = k<256 ? W_ih[g][k] : W_hh[g][k-256]  (384x512)
__global__ void k_transpose(const float* __restrict__ W_in,
                            const float* __restrict__ W_ih,
                            const float* __restrict__ W_hh,
                            float* __restrict__ Wt_in,
                            float* __restrict__ Wt_g) {
    int idx = blockIdx.x * 256 + threadIdx.x;
    if (idx < D_INP * D_HID) {
        int k = idx / D_HID, d = idx % D_HID;
        Wt_in[idx] = W_in[d * D_INP + k];
    }
    if (idx < 384 * 512) {
        int k = idx / 512, g = idx % 512;
        Wt_g[idx] = (k < 256) ? W_ih[g * 256 + k] : W_hh[g * 128 + (k - 256)];
    }
}

// ---------------------------------------------------------------------------
// CSR build: count in-degree at dst
__global__ void k_count(const int* __restrict__ dst, int* __restrict__ cnt) {
    int e = blockIdx.x * 256 + threadIdx.x;
    if (e < N_EDGES) atomicAdd(&cnt[dst[e]], 1);
}

// Phase 1: per-block (512-wide) exclusive scan of cnt; block totals to partials
__global__ __launch_bounds__(512) void k_scan_block(const int* __restrict__ cnt,
                                                    int* __restrict__ row_ptr,
                                                    int* __restrict__ partials,
                                                    float* __restrict__ deg_f) {
    __shared__ int sm[512];
    int i = blockIdx.x * 512 + threadIdx.x;
    int v = (i < N_NODES) ? cnt[i] : 0;
    sm[threadIdx.x] = v;
    __syncthreads();
    for (int off = 1; off < 512; off <<= 1) {
        int u = (threadIdx.x >= off) ? sm[threadIdx.x - off] : 0;
        __syncthreads();
        sm[threadIdx.x] += u;
        __syncthreads();
    }
    if (i < N_NODES) {
        row_ptr[i] = sm[threadIdx.x] - v;      // exclusive within block
        deg_f[i] = (float)max(v, 1);
    }
    if (threadIdx.x == 511) partials[blockIdx.x] = sm[511];
}

// Phase 2: single small block scans the 98 partials into exclusive offsets
__global__ __launch_bounds__(128) void k_scan_part(int* __restrict__ partials,
                                                   int* __restrict__ row_ptr) {
    __shared__ int sm[128];
    int t = threadIdx.x;
    int v = (t < SCAN_NB) ? partials[t] : 0;
    sm[t] = v;
    __syncthreads();
    for (int off = 1; off < 128; off <<= 1) {
        int u = (t >= off) ? sm[t - off] : 0;
        __syncthreads();
        sm[t] += u;
        __syncthreads();
    }
    if (t < SCAN_NB) partials[t] = sm[t] - v;  // exclusive block offset
    if (t == 127) row_ptr[N_NODES] = sm[127];  // grand total (= N_EDGES)
}

// Phase 3: add block offsets; also re-zero cnt for the scatter pass
__global__ __launch_bounds__(512) void k_scan_add(int* __restrict__ row_ptr,
                                                  const int* __restrict__ partials,
                                                  int* __restrict__ cnt) {
    int i = blockIdx.x * 512 + threadIdx.x;
    if (i < N_NODES) {
        row_ptr[i] += partials[blockIdx.x];
        cnt[i] = 0;
    }
}

// Scatter edge src ids into dst-sorted order
__global__ void k_scatter(const int* __restrict__ src, const int* __restrict__ dst,
                          const int* __restrict__ row_ptr, int* __restrict__ cnt,
                          int* __restrict__ esrc) {
    int e = blockIdx.x * 256 + threadIdx.x;
    if (e < N_EDGES) {
        int d = dst[e];
        int p = row_ptr[d] + atomicAdd(&cnt[d], 1);
        esrc[p] = src[e];
    }
}

// seg_ptr for sorted batch: seg_ptr[b] = first node of graph b; seg_ptr[B]=N
__global__ void k_segptr(const int* __restrict__ batch, int* __restrict__ seg_ptr) {
    int n = blockIdx.x * 256 + threadIdx.x;
    if (n >= N_NODES) return;
    int bc = batch[n];
    int bp = (n == 0) ? -1 : batch[n - 1];
    for (int b = bp + 1; b <= bc; b++) seg_ptr[b] = n;
    if (n == N_NODES - 1)
        for (int b = bc + 1; b <= N_B; b++) seg_ptr[b] = N_NODES;
}

// ---------------------------------------------------------------------------
// Input layer: h = relu(x @ W_in^T + b_in).  Tile 64 nodes x 64 feats,
// thread micro-tile 4x4, K=96 fully staged in LDS.
__global__ __launch_bounds__(256) void k_ingemm(const float* __restrict__ x,
                                                const float* __restrict__ Wt_in,
                                                const float* __restrict__ b_in,
                                                float* __restrict__ h) {
    __shared__ __align__(16) float xs[64 * 96];   // 24 KB
    __shared__ __align__(16) float ws[96 * 64];   // 24 KB
    int n0 = blockIdx.x * 64;
    int d0 = blockIdx.y * 64;
    int tid = threadIdx.x;
    for (int j = tid; j < 64 * 96 / 4; j += 256) {
        int node = n0 + (j * 4) / 96;
        float4 v = make_float4(0.f, 0.f, 0.f, 0.f);
        if (node < N_NODES) v = *(const float4*)&x[n0 * 96 + j * 4];
        *(float4*)&xs[j * 4] = v;
    }
    for (int j = tid; j < 96 * 64 / 4; j += 256) {
        int k = (j * 4) / 64, dd = (j * 4) % 64;
        *(float4*)&ws[j * 4] = *(const float4*)&Wt_in[k * D_HID + d0 + dd];
    }
    __syncthreads();
    int tn = tid / 16;       // node sub-tile (4 nodes)
    int td = tid % 16;       // feat sub-tile (4 feats)
    float acc[4][4] = {};
    for (int k0 = 0; k0 < 96; k0 += 4) {
        float4 w0 = *(float4*)&ws[(k0 + 0) * 64 + td * 4];
        float4 w1 = *(float4*)&ws[(k0 + 1) * 64 + td * 4];
        float4 w2 = *(float4*)&ws[(k0 + 2) * 64 + td * 4];
        float4 w3 = *(float4*)&ws[(k0 + 3) * 64 + td * 4];
#pragma unroll
        for (int j = 0; j < 4; j++) {
            float4 xv = *(float4*)&xs[(tn * 4 + j) * 96 + k0];
            acc[j][0] += xv.x * w0.x + xv.y * w1.x + xv.z * w2.x + xv.w * w3.x;
            acc[j][1] += xv.x * w0.y + xv.y * w1.y + xv.z * w2.y + xv.w * w3.y;
            acc[j][2] += xv.x * w0.z + xv.y * w1.z + xv.z * w2.z + xv.w * w3.z;
            acc[j][3] += xv.x * w0.w + xv.y * w1.w + xv.z * w2.w + xv.w * w3.w;
        }
    }
    float4 bb = *(const float4*)&b_in[d0 + td * 4];
#pragma unroll
    for (int j = 0; j < 4; j++) {
        int node = n0 + tn * 4 + j;
        if (node < N_NODES) {
            float4 o;
            o.x = fmaxf(acc[j][0] + bb.x, 0.f);
            o.y = fmaxf(acc[j][1] + bb.y, 0.f);
            o.z = fmaxf(acc[j][2] + bb.z, 0.f);
            o.w = fmaxf(acc[j][3] + bb.w, 0.f);
            *(float4*)&h[node * D_HID + d0 + td * 4] = o;
        }
    }
}

// ---------------------------------------------------------------------------
// One MPNN step: h_out = (h_in + segmean(h_in[src] at dst)) * 0.5
// 32-lane group per node, float4 per lane (contiguous 512B per gather).
__global__ __launch_bounds__(256) void k_mpnn(const float* __restrict__ hin,
                                              float* __restrict__ hout,
                                              const int* __restrict__ row_ptr,
                                              const int* __restrict__ esrc,
                                              const float* __restrict__ deg_f) {
    int g = threadIdx.x >> 5;
    int l = threadIdx.x & 31;
    int n = blockIdx.x * 8 + g;
    if (n >= N_NODES) return;
    int s0 = row_ptr[n], s1 = row_ptr[n + 1];
    float4 acc = make_float4(0.f, 0.f, 0.f, 0.f);
    for (int i = s0; i < s1; i++) {
        int s = esrc[i];
        float4 v = *(const float4*)&hin[s * D_HID + l * 4];
        acc.x += v.x; acc.y += v.y; acc.z += v.z; acc.w += v.w;
    }
    float invd = 1.0f / deg_f[n];
    float4 hv = *(const float4*)&hin[n * D_HID + l * 4];
    float4 o;
    o.x = (hv.x + acc.x * invd) * 0.5f;
    o.y = (hv.y + acc.y * invd) * 0.5f;
    o.z = (hv.z + acc.z * invd) * 0.5f;
    o.w = (hv.w + acc.w * invd) * 0.5f;
    *(float4*)&hout[n * D_HID + l * 4] = o;
}

// ---------------------------------------------------------------------------
// gates = [q_star | hh] @ Wt_g + (b_ih + b_hh).  Tile: 4 b-rows x 256 gates,
// thread computes 4x2, K=384 (A-tile in LDS, W streamed coalesced).
__global__ __launch_bounds__(128) void k_gates(const float* __restrict__ qstar,
                                               const float* __restrict__ hh,
                                               const float* __restrict__ Wt_g,
                                               const float* __restrict__ b_ih,
                                               const float* __restrict__ b_hh,
                                               float* __restrict__ gates) {
    __shared__ __align__(16) float als[4 * 384];
    int b0 = blockIdx.x * 4;
    int g0 = blockIdx.y * 256;
    int tid = threadIdx.x;
    for (int i = tid; i < 4 * 384; i += 128) {
        int bb = i / 384, k = i % 384;
        als[i] = (k < 256) ? qstar[(b0 + bb) * 256 + k]
                           : hh[(b0 + bb) * 128 + (k - 256)];
    }
    __syncthreads();
    int g = g0 + tid * 2;
    float2 acc0 = {0.f, 0.f}, acc1 = {0.f, 0.f}, acc2 = {0.f, 0.f}, acc3 = {0.f, 0.f};
    for (int k0 = 0; k0 < 384; k0 += 4) {
        float4 a0 = *(float4*)&als[0 * 384 + k0];
        float4 a1 = *(float4*)&als[1 * 384 + k0];
        float4 a2 = *(float4*)&als[2 * 384 + k0];
        float4 a3 = *(float4*)&als[3 * 384 + k0];
        float2 w;
        w = *(const float2*)&Wt_g[(k0 + 0) * 512 + g];
        acc0.x += a0.x * w.x; acc0.y += a0.x * w.y;
        acc1.x += a1.x * w.x; acc1.y += a1.x * w.y;
        acc2.x += a2.x * w.x; acc2.y += a2.x * w.y;
        acc3.x += a3.x * w.x; acc3.y += a3.x * w.y;
        w = *(const float2*)&Wt_g[(k0 + 1) * 512 + g];
        acc0.x += a0.y * w.x; acc0.y += a0.y * w.y;
        acc1.x += a1.y * w.x; acc1.y += a1.y * w.y;
        acc2.x += a2.y * w.x; acc2.y += a2.y * w.y;
        acc3.x += a3.y * w.x; acc3.y += a3.y * w.y;
        w = *(const float2*)&Wt_g[(k0 + 2) * 512 + g];
        acc0.x += a0.z * w.x; acc0.y += a0.z * w.y;
        acc1.x += a1.z * w.x; acc1.y += a1.z * w.y;
        acc2.x += a2.z * w.x; acc2.y += a2.z * w.y;
        acc3.x += a3.z * w.x; acc3.y += a3.z * w.y;
        w = *(const float2*)&Wt_g[(k0 + 3) * 512 + g];
        acc0.x += a0.w * w.x; acc0.y += a0.w * w.y;
        acc1.x += a1.w * w.x; acc1.y += a1.w * w.y;
        acc2.x += a2.w * w.x; acc2.y += a2.w * w.y;
        acc3.x += a3.w * w.x; acc3.y += a3.w * w.y;
    }
    float bias0 = b_ih[g] + b_hh[g];
    float bias1 = b_ih[g + 1] + b_hh[g + 1];
    float2 o;
    o.x = acc0.x + bias0; o.y = acc0.y + bias1;
    *(float2*)&gates[(b0 + 0) * 512 + g] = o;
    o.x = acc1.x + bias0; o.y = acc1.y + bias1;
    *(float2*)&gates[(b0 + 1) * 512 + g] = o;
    o.x = acc2.x + bias0; o.y = acc2.y + bias1;
    *(float2*)&gates[(b0 + 2) * 512 + g] = o;
    o.x = acc3.x + bias0; o.y = acc3.y + bias1;
    *(float2*)&gates[(b0 + 3) * 512 + g] = o;
}

__device__ __forceinline__ float sigmoidf_(float v) { return 1.0f / (1.0f + expf(-v)); }

// LSTM elementwise; writes hh, cc and q into q_star[:, :128]
__global__ void k_lstm(const float* __restrict__ gates, float* __restrict__ hh,
                       float* __restrict__ cc, float* __restrict__ qstar) {
    int idx = blockIdx.x * 256 + threadIdx.x;   // < B*D = 65536
    int b = idx >> 7, dd = idx & 127;
    const float* gr = &gates[b * 512];
    float ig = gr[dd], fg = gr[128 + dd], gg = gr[256 + dd], og = gr[384 + dd];
    float c = sigmoidf_(fg) * cc[idx] + sigmoidf_(ig) * tanhf(gg);
    cc[idx] = c;
    float hv = sigmoidf_(og) * tanhf(c);
    hh[idx] = hv;
    qstar[b * 256 + dd] = hv;
}

// Segment attention: e = h.q[batch], softmax per graph, r = sum a*h.
// One block per graph (batch is sorted -> contiguous node range).
__global__ __launch_bounds__(128) void k_attn(const float* __restrict__ h,
                                              const float* __restrict__ hh,
                                              const int* __restrict__ seg_ptr,
                                              float* __restrict__ e_buf,
                                              float* __restrict__ qstar) {
    int b = blockIdx.x;
    int g = threadIdx.x >> 5, l = threadIdx.x & 31;
    int s0 = seg_ptr[b], s1 = seg_ptr[b + 1];
    float4 q = *(const float4*)&hh[b * 128 + l * 4];
    float lmax = -INFINITY;
    for (int n = s0 + g; n < s1; n += 4) {
        float4 hv = *(const float4*)&h[n * 128 + l * 4];
        float d = hv.x * q.x + hv.y * q.y + hv.z * q.z + hv.w * q.w;
        for (int m = 16; m >= 1; m >>= 1) d += __shfl_xor(d, m, 64);
        if (l == 0) e_buf[n] = d;
        lmax = fmaxf(lmax, d);
    }
    __shared__ float smax[4];
    __shared__ float ssum[4];
    __shared__ __align__(16) float sr[4][128];
    if (l == 0) smax[g] = lmax;
    __syncthreads();
    float M = fmaxf(fmaxf(smax[0], smax[1]), fmaxf(smax[2], smax[3]));
    float4 racc = make_float4(0.f, 0.f, 0.f, 0.f);
    float asum = 0.f;
    for (int n = s0 + g; n < s1; n += 4) {
        float a = expf(e_buf[n] - M);
        asum += a;
        float4 hv = *(const float4*)&h[n * 128 + l * 4];
        racc.x += a * hv.x; racc.y += a * hv.y;
        racc.z += a * hv.z; racc.w += a * hv.w;
    }
    if (l == 0) ssum[g] = asum;
    *(float4*)&sr[g][l * 4] = racc;
    __syncthreads();
    if (g == 0) {
        float4 r0 = *(float4*)&sr[0][l * 4];
        float4 r1 = *(float4*)&sr[1][l * 4];
        float4 r2 = *(float4*)&sr[2][l * 4];
        float4 r3 = *(float4*)&sr[3][l * 4];
        float inv = 1.0f / (ssum[0] + ssum[1] + ssum[2] + ssum[3] + 1e-16f);
        float4 o;
        o.x = (r0.x + r1.x + r2.x + r3.x) * inv;
        o.y = (r0.y + r1.y + r2.y + r3.y) * inv;
        o.z = (r0.z + r1.z + r2.z + r3.z) * inv;
        o.w = (r0.w + r1.w + r2.w + r3.w) * inv;
        *(float4*)&qstar[b * 256 + 128 + l * 4] = o;
    }
}

// out[b] = q_star[b] . W_pred + b_pred  (one wave per b)
__global__ void k_pred(const float* __restrict__ qstar, const float* __restrict__ W_pred,
                       const float* __restrict__ b_pred, float* __restrict__ out) {
    int w = (blockIdx.x * 256 + threadIdx.x) >> 6;
    int l = threadIdx.x & 63;
    if (w >= N_B) return;
    float4 qv = *(const float4*)&qstar[w * 256 + l * 4];
    float4 wv = *(const float4*)&W_pred[l * 4];
    float d = qv.x * wv.x + qv.y * wv.y + qv.z * wv.z + qv.w * wv.w;
    for (int m = 32; m >= 1; m >>= 1) d += __shfl_xor(d, m, 64);
    if (l == 0) out[w] = d + b_pred[0];
}

// ---------------------------------------------------------------------------
extern "C" void kernel_launch(void* const* d_in, const int* in_sizes, int n_in,
                              void* d_out, int out_size, void* d_ws, size_t ws_size,
                              hipStream_t stream) {
    const float* x      = (const float*)d_in[0];
    const int*   edge   = (const int*)d_in[1];
    const int*   batch  = (const int*)d_in[2];
    const float* W_in   = (const float*)d_in[3];
    const float* b_in   = (const float*)d_in[4];
    const float* W_ih   = (const float*)d_in[5];
    const float* W_hh   = (const float*)d_in[6];
    const float* b_ih   = (const float*)d_in[7];
    const float* b_hh   = (const float*)d_in[8];
    const float* W_pred = (const float*)d_in[9];
    const float* b_pred = (const float*)d_in[10];
    float* out = (float*)d_out;

    const int* src = edge;              // edge_index[0]
    const int* dst = edge + N_EDGES;    // edge_index[1]

    // workspace layout (floats first, 16B-aligned throughout)
    float* f = (float*)d_ws;
    float* h0    = f;                     f += (size_t)N_NODES * D_HID;   // 6.4M
    float* h1    = f;                     f += (size_t)N_NODES * D_HID;   // 6.4M
    float* deg_f = f;                     f += N_NODES;
    float* e_buf = f;                     f += N_NODES + 12;              // keep 16B align
    float* qstar = f;                     f += (size_t)N_B * 256;
    float* hh    = f;                     f += (size_t)N_B * 128;
    float* cc    = f;                     f += (size_t)N_B * 128;
    float* gates = f;                     f += (size_t)N_B * 512;
    float* Wt_in = f;                     f += D_INP * D_HID;
    float* Wt_g  = f;                     f += 384 * 512;
    int* ip = (int*)f;
    int* row_ptr = ip;                    ip += N_NODES + 1;
    int* cnt     = ip;                    ip += N_NODES;
    int* esrc    = ip;                    ip += N_EDGES;
    int* seg_ptr = ip;                    ip += N_B + 1;
    int* partials = ip;                   ip += 128;

    // ---- CSR build + seg_ptr + weight transposes
    hipMemsetAsync(cnt, 0, N_NODES * sizeof(int), stream);
    k_transpose<<<768, 256, 0, stream>>>(W_in, W_ih, W_hh, Wt_in, Wt_g);
    k_count<<<(N_EDGES + 255) / 256, 256, 0, stream>>>(dst, cnt);
    k_scan_block<<<SCAN_NB, 512, 0, stream>>>(cnt, row_ptr, partials, deg_f);
    k_scan_part<<<1, 128, 0, stream>>>(partials, row_ptr);
    k_scan_add<<<SCAN_NB, 512, 0, stream>>>(row_ptr, partials, cnt);  // also zeroes cnt
    k_scatter<<<(N_EDGES + 255) / 256, 256, 0, stream>>>(src, dst, row_ptr, cnt, esrc);
    k_segptr<<<(N_NODES + 255) / 256, 256, 0, stream>>>(batch, seg_ptr);

    // ---- input layer
    k_ingemm<<<dim3((N_NODES + 63) / 64, 2), 256, 0, stream>>>(x, Wt_in, b_in, h0);

    // ---- 4 MPNN steps (ping-pong, ends in h0)
    k_mpnn<<<(N_NODES + 7) / 8, 256, 0, stream>>>(h0, h1, row_ptr, esrc, deg_f);
    k_mpnn<<<(N_NODES + 7) / 8, 256, 0, stream>>>(h1, h0, row_ptr, esrc, deg_f);
    k_mpnn<<<(N_NODES + 7) / 8, 256, 0, stream>>>(h0, h1, row_ptr, esrc, deg_f);
    k_mpnn<<<(N_NODES + 7) / 8, 256, 0, stream>>>(h1, h0, row_ptr, esrc, deg_f);

    // ---- Set2Set (q_star, hh, cc are contiguous -> one memset)
    hipMemsetAsync(qstar, 0, (size_t)(N_B * 256 + N_B * 128 + N_B * 128) * sizeof(float), stream);
    for (int step = 0; step < 3; step++) {
        k_gates<<<dim3(N_B / 4, 2), 128, 0, stream>>>(qstar, hh, Wt_g, b_ih, b_hh, gates);
        k_lstm<<<(N_B * 128) / 256, 256, 0, stream>>>(gates, hh, cc, qstar);
        k_attn<<<N_B, 128, 0, stream>>>(h0, hh, seg_ptr, e_buf, qstar);
    }

    // ---- prediction head
    k_pred<<<(N_B * 64) / 256, 256, 0, stream>>>(qstar, W_pred, b_pred, out);
}